// Round 10
// baseline (383.471 us; speedup 1.0000x reference)
//
#include <hip/hip_runtime.h>

#define Bq 128
#define Sq 512
#define Cq 37
#define Dq 768
#define VST 40   // vhist row stride in floats

static __device__ __forceinline__ float bcast(float v, int p) {
  return __int_as_float(__builtin_amdgcn_ds_bpermute(p << 2, __float_as_int(v)));
}

#define REP37(X) X(0)X(1)X(2)X(3)X(4)X(5)X(6)X(7)X(8)X(9)X(10)X(11)X(12)X(13) \
  X(14)X(15)X(16)X(17)X(18)X(19)X(20)X(21)X(22)X(23)X(24)X(25)X(26)X(27)X(28) \
  X(29)X(30)X(31)X(32)X(33)X(34)X(35)X(36)

// ---------------- Kernel 0: transpose W -> Wt[c][d] ----------------
__global__ __launch_bounds__(256) void prep_kernel(
    const float* __restrict__ W, float* __restrict__ Wt)
{
  for (int i = blockIdx.x * 256 + threadIdx.x; i < Dq * Cq; i += gridDim.x * 256) {
    int d = i / Cq, c = i % Cq;
    Wt[(size_t)c * Dq + d] = W[i];
  }
}

// ---------------- Kernel 1: emissions = x @ W + b ----------------
// No LDS, no barriers. 2 tokens/thread; W via wave-uniform pointers
// (scalarizable to s_load, L2-hot); x per-lane float4.
__global__ __launch_bounds__(256) void emis_kernel(
    const float* __restrict__ x, const float* __restrict__ Wt,
    const float* __restrict__ bias, float* __restrict__ em)
{
  int tid = threadIdx.x, lane = tid & 63;
  int wq = __builtin_amdgcn_readfirstlane(tid >> 6);    // 0..3, uniform
  int tok = blockIdx.x * 128 + lane;                    // and tok+64
  const float* xr0 = x + (size_t)tok * Dq;
  const float* xr1 = xr0 + (size_t)64 * Dq;
  float acc0[10], acc1[10];
#pragma unroll
  for (int k = 0; k < 10; ++k) { acc0[k] = 0.f; acc1[k] = 0.f; }

#pragma unroll 2
  for (int d0 = 0; d0 < Dq; d0 += 32) {
    float4 xa[8], xb[8];
#pragma unroll
    for (int q = 0; q < 8; ++q) {
      xa[q] = *(const float4*)(xr0 + d0 + q * 4);
      xb[q] = *(const float4*)(xr1 + d0 + q * 4);
    }
#pragma unroll
    for (int k = 0; k < 10; ++k) {
      int cc = wq + 4 * k;                              // uniform
      if (cc < Cq) {
        const float4* wr = (const float4*)(Wt + (size_t)cc * Dq + d0);
        float a0 = acc0[k], a1 = acc1[k];
#pragma unroll
        for (int q = 0; q < 8; ++q) {
          float4 w = wr[q];
          a0 += xa[q].x * w.x; a0 += xa[q].y * w.y;
          a0 += xa[q].z * w.z; a0 += xa[q].w * w.w;
          a1 += xb[q].x * w.x; a1 += xb[q].y * w.y;
          a1 += xb[q].z * w.z; a1 += xb[q].w * w.w;
        }
        acc0[k] = a0; acc1[k] = a1;
      }
    }
  }
#pragma unroll
  for (int k = 0; k < 10; ++k) {
    int cc = wq + 4 * k;
    if (cc < Cq) {
      em[(size_t)tok * Cq + cc] = acc0[k] + bias[cc];
      em[(size_t)(tok + 64) * Cq + cc] = acc1[k] + bias[cc];
    }
  }
}

// ---------------- Kernel 2: CRF serial chains, 2 sequences per wave ----------------
// Blocks 0-63: fwd (wave0, 2 seqs interleaved) + gold (wave1).
// Blocks 64-127: viterbi (wave0, 2 seqs interleaved).
// Each seq's ds_write->ds_read round trip hides under the other's compute.
__global__ __launch_bounds__(128) void crf_fb_kernel(
    const float* __restrict__ em, const float* __restrict__ startv,
    const float* __restrict__ endv, const float* __restrict__ trans,
    const int* __restrict__ labels, const unsigned char* __restrict__ maskb,
    float* __restrict__ vhist, float* __restrict__ scorep,
    float* __restrict__ logZp, int* __restrict__ lenp, int* __restrict__ lastp)
{
  __shared__ float sA[64], sB[64];
  int role = blockIdx.x >> 6, pair = blockIdx.x & 63;
  int b0 = pair * 2, b1 = b0 + 1;
  int tid = threadIdx.x, wid = tid >> 6, lane = tid & 63;
  int cl = lane < Cq ? lane : Cq - 1;
  const float L2E = 1.4426950408889634f, LN2 = 0.6931471805599453f;

  int esz4 = (maskb[1] == 0) ? 1 : 0;
  int lenA = 0, lenB = 0;
#pragma unroll
  for (int k = 0; k < 8; ++k) {
    size_t t = (size_t)lane + (size_t)k * 64;
    lenA += (maskb[esz4 ? ((size_t)b0 * Sq + t) * 4 : (size_t)b0 * Sq + t] != 0);
    lenB += (maskb[esz4 ? ((size_t)b1 * Sq + t) * 4 : (size_t)b1 * Sq + t] != 0);
  }
#pragma unroll
  for (int off = 32; off; off >>= 1) {
    lenA += __shfl_xor(lenA, off);
    lenB += __shfl_xor(lenB, off);
  }
  int tmax = lenA > lenB ? lenA : lenB;
  const float* eA = em + (size_t)b0 * Sq * Cq;
  const float* eB = em + (size_t)b1 * Sq * Cq;

  if (role == 0 && wid == 0) {
    // ---- forward, exp domain (R8 math + K restored), 2-seq pipeline ----
    float E[Cq];
#pragma unroll
    for (int p = 0; p < Cq; ++p) E[p] = exp2f(trans[p * Cq + cl] * L2E);
    float iA = (lane < Cq) ? (startv[cl] + eA[cl]) : -3.0e38f;
    float KA = bcast(iA, 0);
    float ezA = (lane < Cq) ? exp2f((iA - KA) * L2E) : 0.f;
    float iB = (lane < Cq) ? (startv[cl] + eB[cl]) : -3.0e38f;
    float KB = bcast(iB, 0);
    float ezB = (lane < Cq) ? exp2f((iB - KB) * L2E) : 0.f;
    int eaA = 0, eaB = 0;
    float wA0 = exp2f(eA[1 * Cq + cl] * L2E), wA1 = exp2f(eA[2 * Cq + cl] * L2E);
    float wA2 = exp2f(eA[3 * Cq + cl] * L2E), wA3 = exp2f(eA[4 * Cq + cl] * L2E);
    float wB0 = exp2f(eB[1 * Cq + cl] * L2E), wB1 = exp2f(eB[2 * Cq + cl] * L2E);
    float wB2 = exp2f(eB[3 * Cq + cl] * L2E), wB3 = exp2f(eB[4 * Cq + cl] * L2E);
    float gA[40], gB[40];
    float4* gA4 = (float4*)gA; float4* gB4 = (float4*)gB;
    const float4* sA4 = (const float4*)sA; const float4* sB4 = (const float4*)sB;
    sA[lane] = ezA;
#pragma unroll
    for (int q = 0; q < 10; ++q) gA4[q] = sA4[q];
    sB[lane] = ezB;
#pragma unroll
    for (int q = 0; q < 10; ++q) gB4[q] = sB4[q];

    for (int t = 1; t < tmax; ++t) {
      { // ---- seq A step ----
        int e0 = ((__float_as_int(gA[0]) >> 23) & 255) - 127;
        float sc = __int_as_float((127 - e0) << 23);
        float s0 = 0.f, s1 = 0.f, s2 = 0.f, s3 = 0.f;
#pragma unroll
        for (int p = 0; p < Cq; p += 4) {
          s0 = fmaf(gA[p], E[p], s0);
          if (p + 1 < Cq) s1 = fmaf(gA[p + 1], E[p + 1], s1);
          if (p + 2 < Cq) s2 = fmaf(gA[p + 2], E[p + 2], s2);
          if (p + 3 < Cq) s3 = fmaf(gA[p + 3], E[p + 3], s3);
        }
        float dot = (s0 + s1) + (s2 + s3);
        float wcur = wA0; wA0 = wA1; wA1 = wA2; wA2 = wA3;
        int tn = (t + 4 < lenA) ? t + 4 : lenA - 1;
        wA3 = exp2f(eA[(size_t)tn * Cq + cl] * L2E);
        bool live = t < lenA;
        ezA = live ? dot * (wcur * sc) : ezA;
        eaA += live ? e0 : 0;
        sA[lane] = ezA;
#pragma unroll
        for (int q = 0; q < 10; ++q) gA4[q] = sA4[q];
      }
      { // ---- seq B step (round trip of A hides here) ----
        int e0 = ((__float_as_int(gB[0]) >> 23) & 255) - 127;
        float sc = __int_as_float((127 - e0) << 23);
        float s0 = 0.f, s1 = 0.f, s2 = 0.f, s3 = 0.f;
#pragma unroll
        for (int p = 0; p < Cq; p += 4) {
          s0 = fmaf(gB[p], E[p], s0);
          if (p + 1 < Cq) s1 = fmaf(gB[p + 1], E[p + 1], s1);
          if (p + 2 < Cq) s2 = fmaf(gB[p + 2], E[p + 2], s2);
          if (p + 3 < Cq) s3 = fmaf(gB[p + 3], E[p + 3], s3);
        }
        float dot = (s0 + s1) + (s2 + s3);
        float wcur = wB0; wB0 = wB1; wB1 = wB2; wB2 = wB3;
        int tn = (t + 4 < lenB) ? t + 4 : lenB - 1;
        wB3 = exp2f(eB[(size_t)tn * Cq + cl] * L2E);
        bool live = t < lenB;
        ezB = live ? dot * (wcur * sc) : ezB;
        eaB += live ? e0 : 0;
        sB[lane] = ezB;
#pragma unroll
        for (int q = 0; q < 10; ++q) gB4[q] = sB4[q];
      }
    }
    { // epilogue A
      float xv = (lane < Cq) ? LN2 * (log2f(ezA) + (float)eaA) + KA + endv[cl] : -3.0e38f;
      float mm = xv;
#pragma unroll
      for (int off = 32; off; off >>= 1) mm = fmaxf(mm, __shfl_xor(mm, off));
      float es = exp2f((xv - mm) * L2E);
#pragma unroll
      for (int off = 32; off; off >>= 1) es += __shfl_xor(es, off);
      if (lane == 0) logZp[b0] = mm + log2f(es) * LN2;
    }
    { // epilogue B
      float xv = (lane < Cq) ? LN2 * (log2f(ezB) + (float)eaB) + KB + endv[cl] : -3.0e38f;
      float mm = xv;
#pragma unroll
      for (int off = 32; off; off >>= 1) mm = fmaxf(mm, __shfl_xor(mm, off));
      float es = exp2f((xv - mm) * L2E);
#pragma unroll
      for (int off = 32; off; off >>= 1) es += __shfl_xor(es, off);
      if (lane == 0) logZp[b1] = mm + log2f(es) * LN2;
    }
  } else if (role == 0 && wid == 1) {
    // ---- gold path score, both seqs ----
#pragma unroll
    for (int s = 0; s < 2; ++s) {
      int bb = s ? b1 : b0;
      int lenS = s ? lenB : lenA;
      const int* lab = labels + (size_t)bb * Sq;
      const float* eS = s ? eB : eA;
      float scr = 0.f;
#pragma unroll
      for (int k = 0; k < 8; ++k) {
        int t = 1 + lane + k * 64;
        if (t < lenS) {
          int lp = lab[t - 1], lt = lab[t];
          scr += trans[lp * Cq + lt] + eS[(size_t)t * Cq + lt];
        }
      }
#pragma unroll
      for (int off = 32; off; off >>= 1) scr += __shfl_xor(scr, off);
      if (lane == 0) {
        int l0 = lab[0], lf = lab[lenS - 1];
        scorep[bb] = scr + startv[l0] + eS[l0] + endv[lf];
      }
    }
  } else if (role == 1 && wid == 0) {
    // ---- viterbi values, 2-seq pipeline (candidates in reference order) ----
    float T[Cq];
#pragma unroll
    for (int p = 0; p < Cq; ++p) T[p] = trans[p * Cq + cl];
    float vA = (lane < Cq) ? (startv[cl] + eA[cl]) : -3.0e38f;
    float vB = (lane < Cq) ? (startv[cl] + eB[cl]) : -3.0e38f;
    if (lane < Cq) {
      vhist[((size_t)b0 * Sq) * VST + cl] = vA;
      vhist[((size_t)b1 * Sq) * VST + cl] = vB;
    }
    float mA0 = eA[1 * Cq + cl], mA1 = eA[2 * Cq + cl];
    float mA2 = eA[3 * Cq + cl], mA3 = eA[4 * Cq + cl];
    float mB0 = eB[1 * Cq + cl], mB1 = eB[2 * Cq + cl];
    float mB2 = eB[3 * Cq + cl], mB3 = eB[4 * Cq + cl];
    float gA[40], gB[40];
    float4* gA4 = (float4*)gA; float4* gB4 = (float4*)gB;
    const float4* sA4 = (const float4*)sA; const float4* sB4 = (const float4*)sB;
    sA[lane] = vA;
#pragma unroll
    for (int q = 0; q < 10; ++q) gA4[q] = sA4[q];
    sB[lane] = vB;
#pragma unroll
    for (int q = 0; q < 10; ++q) gB4[q] = sB4[q];

    for (int t = 1; t < tmax; ++t) {
      { // seq A
        float c0 = -3.0e38f, c1 = -3.0e38f, c2 = -3.0e38f, c3 = -3.0e38f;
#pragma unroll
        for (int p = 0; p < Cq; p += 4) {
          c0 = fmaxf(c0, gA[p] + T[p]);
          if (p + 1 < Cq) c1 = fmaxf(c1, gA[p + 1] + T[p + 1]);
          if (p + 2 < Cq) c2 = fmaxf(c2, gA[p + 2] + T[p + 2]);
          if (p + 3 < Cq) c3 = fmaxf(c3, gA[p + 3] + T[p + 3]);
        }
        float best = fmaxf(fmaxf(c0, c1), fmaxf(c2, c3));
        float mcur = mA0; mA0 = mA1; mA1 = mA2; mA2 = mA3;
        int tn = (t + 4 < lenA) ? t + 4 : lenA - 1;
        mA3 = eA[(size_t)tn * Cq + cl];
        bool live = t < lenA;
        vA = (live && lane < Cq) ? best + mcur : vA;
        if (live && lane < Cq) vhist[((size_t)b0 * Sq + t) * VST + cl] = vA;
        sA[lane] = vA;
#pragma unroll
        for (int q = 0; q < 10; ++q) gA4[q] = sA4[q];
      }
      { // seq B
        float c0 = -3.0e38f, c1 = -3.0e38f, c2 = -3.0e38f, c3 = -3.0e38f;
#pragma unroll
        for (int p = 0; p < Cq; p += 4) {
          c0 = fmaxf(c0, gB[p] + T[p]);
          if (p + 1 < Cq) c1 = fmaxf(c1, gB[p + 1] + T[p + 1]);
          if (p + 2 < Cq) c2 = fmaxf(c2, gB[p + 2] + T[p + 2]);
          if (p + 3 < Cq) c3 = fmaxf(c3, gB[p + 3] + T[p + 3]);
        }
        float best = fmaxf(fmaxf(c0, c1), fmaxf(c2, c3));
        float mcur = mB0; mB0 = mB1; mB1 = mB2; mB2 = mB3;
        int tn = (t + 4 < lenB) ? t + 4 : lenB - 1;
        mB3 = eB[(size_t)tn * Cq + cl];
        bool live = t < lenB;
        vB = (live && lane < Cq) ? best + mcur : vB;
        if (live && lane < Cq) vhist[((size_t)b1 * Sq + t) * VST + cl] = vB;
        sB[lane] = vB;
#pragma unroll
        for (int q = 0; q < 10; ++q) gB4[q] = sB4[q];
      }
    }
    { // argmax epilogues
      float xv = (lane < Cq) ? vA + endv[cl] : -3.0e38f;
      int idx = (lane < Cq) ? lane : 1000;
#pragma unroll
      for (int off = 32; off; off >>= 1) {
        float xo = __shfl_xor(xv, off); int io = __shfl_xor(idx, off);
        if (xo > xv || (xo == xv && io < idx)) { xv = xo; idx = io; }
      }
      if (lane == 0) { lastp[b0] = idx; lenp[b0] = lenA; }
      xv = (lane < Cq) ? vB + endv[cl] : -3.0e38f;
      idx = (lane < Cq) ? lane : 1000;
#pragma unroll
      for (int off = 32; off; off >>= 1) {
        float xo = __shfl_xor(xv, off); int io = __shfl_xor(idx, off);
        if (xo > xv || (xo == xv && io < idx)) { xv = xo; idx = io; }
      }
      if (lane == 0) { lastp[b1] = idx; lenp[b1] = lenB; }
    }
  }
}

// ---------------- Kernel 3: backpointers (parallel recompute) ----------------
__global__ __launch_bounds__(256) void crf_bp_kernel(
    const float* __restrict__ vhist, const float* __restrict__ trans,
    const int* __restrict__ lenp, unsigned char* __restrict__ bp)
{
  int b = blockIdx.x >> 2, chunk = blockIdx.x & 3;
  int wid = threadIdx.x >> 6, lane = threadIdx.x & 63;
  int cl = lane < Cq ? lane : Cq - 1;
  int len = lenp[b];
#define DECLT(i) float T##i = trans[(i) * Cq + cl];
  REP37(DECLT)
  int tend = 1 + (chunk + 1) * 128; if (tend > len) tend = len;
  int rl9 = lane < VST ? lane : VST - 1;
  for (int t = 1 + chunk * 128 + wid; t < tend; t += 4) {
    float vr = vhist[((size_t)b * Sq + (t - 1)) * VST + rl9];
#define BCASTB(i) float br##i = bcast(vr, (i));
    REP37(BCASTB)
    float best = -3.0e38f; int bi = 0;
#define BARG(i) { float cnd = br##i + T##i; if (cnd > best) { best = cnd; bi = (i); } }
    REP37(BARG)                             // ascending + strict '>' => first-index tie-break
    if (lane < Cq) bp[((size_t)b * VST + cl) * Sq + t] = (unsigned char)bi;
  }
}

// ---------------- Kernel 4: register-resident backtrack ----------------
__global__ __launch_bounds__(64) void crf_back_kernel(
    const unsigned char* __restrict__ bp, const int* __restrict__ lenp,
    const int* __restrict__ lastp, float* __restrict__ outp)
{
  int b = blockIdx.x, lane = threadIdx.x;
  int len = __builtin_amdgcn_readfirstlane(lenp[b]);
  int tag = __builtin_amdgcn_readfirstlane(lastp[b]);
  int row = lane < VST ? lane : VST - 1;
  const uint4* src = (const uint4*)(bp + ((size_t)b * VST + row) * Sq);
  unsigned r[128];
#pragma unroll
  for (int k = 0; k < 32; ++k) {
    uint4 q = src[k];
    r[4 * k] = q.x; r[4 * k + 1] = q.y; r[4 * k + 2] = q.z; r[4 * k + 3] = q.w;
  }
  unsigned vt[8];
#pragma unroll
  for (int j = 0; j < 8; ++j) vt[j] = 0u;
  vt[7] = (lane == 63) ? (unsigned)tag : vt[7];
#pragma unroll
  for (int t = 510; t >= 0; --t) {
    int word = __builtin_amdgcn_readlane((int)r[(t + 1) >> 2], tag);
    int nt = (word >> (((t + 1) & 3) * 8)) & 0xff;
    tag = (t + 1 < len) ? nt : tag;
    vt[t >> 6] = (lane == (t & 63)) ? (unsigned)tag : vt[t >> 6];
  }
#pragma unroll
  for (int j = 0; j < 8; ++j) {
    int t = j * 64 + lane;
    float o = (t < len) ? (float)(int)vt[j] : 36.0f;
    outp[(size_t)b * Sq + t] = o;
  }
}

// ---------------- Kernel 5: reduce ll partials ----------------
__global__ __launch_bounds__(64) void ll_reduce_kernel(
    const float* __restrict__ scorep, const float* __restrict__ logZp,
    float* __restrict__ outp)
{
  int lane = threadIdx.x;
  float s = (scorep[lane] - logZp[lane]) + (scorep[lane + 64] - logZp[lane + 64]);
#pragma unroll
  for (int off = 32; off; off >>= 1) s += __shfl_xor(s, off);
  if (lane == 0) outp[0] = s;
}

extern "C" void kernel_launch(void* const* d_in, const int* in_sizes, int n_in,
                              void* d_out, int out_size, void* d_ws, size_t ws_size,
                              hipStream_t stream)
{
  const float* x      = (const float*)d_in[0];
  const float* W      = (const float*)d_in[1];
  const float* bias   = (const float*)d_in[2];
  const float* startv = (const float*)d_in[3];
  const float* endv   = (const float*)d_in[4];
  const float* trans  = (const float*)d_in[5];
  const int*   labels = (const int*)d_in[6];
  const unsigned char* maskb = (const unsigned char*)d_in[7];
  float* out = (float*)d_out;

  char* ws = (char*)d_ws;
  float* em            = (float*)(ws);                    // 9,699,328 B
  float* vhist         = (float*)(ws + 9699328);          // 10,485,760 B
  unsigned char* bpbuf = (unsigned char*)(ws + 20185088); // 2,621,440 B
  float* scorep        = (float*)(ws + 22806528);
  float* logZp         = (float*)(ws + 22807040);
  int*   lenp          = (int*)(ws + 22807552);
  int*   lastp         = (int*)(ws + 22808064);
  float* Wt            = (float*)(ws + 22808576);         // 113,664 B

  prep_kernel<<<28, 256, 0, stream>>>(W, Wt);
  emis_kernel<<<512, 256, 0, stream>>>(x, Wt, bias, em);
  crf_fb_kernel<<<128, 128, 0, stream>>>(em, startv, endv, trans, labels, maskb,
                                         vhist, scorep, logZp, lenp, lastp);
  crf_bp_kernel<<<512, 256, 0, stream>>>(vhist, trans, lenp, bpbuf);
  crf_back_kernel<<<128, 64, 0, stream>>>(bpbuf, lenp, lastp, out + 1);
  ll_reduce_kernel<<<1, 64, 0, stream>>>(scorep, logZp, out);
}

// Round 11
// 289.032 us; speedup vs baseline: 1.3267x; 1.3267x over previous
//
#include <hip/hip_runtime.h>

#define Bq 128
#define Sq 512
#define Cq 37
#define Dq 768
#define VST 40   // vhist row stride in floats

typedef __attribute__((ext_vector_type(2))) float f32x2;

static __device__ __forceinline__ f32x2 pk_fma(f32x2 a, f32x2 b, f32x2 c) {
  f32x2 d; asm("v_pk_fma_f32 %0, %1, %2, %3" : "=v"(d) : "v"(a), "v"(b), "v"(c));
  return d;
}
static __device__ __forceinline__ f32x2 pk_add(f32x2 a, f32x2 b) {
  f32x2 d; asm("v_pk_add_f32 %0, %1, %2" : "=v"(d) : "v"(a), "v"(b));
  return d;
}
static __device__ __forceinline__ float bcast(float v, int p) {
  return __int_as_float(__builtin_amdgcn_ds_bpermute(p << 2, __float_as_int(v)));
}

#define REP18(X) X(0)X(1)X(2)X(3)X(4)X(5)X(6)X(7)X(8)X(9)X(10)X(11)X(12)X(13) \
  X(14)X(15)X(16)X(17)
#define REP37(X) X(0)X(1)X(2)X(3)X(4)X(5)X(6)X(7)X(8)X(9)X(10)X(11)X(12)X(13) \
  X(14)X(15)X(16)X(17)X(18)X(19)X(20)X(21)X(22)X(23)X(24)X(25)X(26)X(27)X(28) \
  X(29)X(30)X(31)X(32)X(33)X(34)X(35)X(36)

// ---------------- Kernel 0: transpose W -> Wt[c][d] ----------------
__global__ __launch_bounds__(256) void prep_kernel(
    const float* __restrict__ W, float* __restrict__ Wt)
{
  for (int i = blockIdx.x * 256 + threadIdx.x; i < Dq * Cq; i += gridDim.x * 256) {
    int d = i / Cq, c = i % Cq;
    Wt[(size_t)c * Dq + d] = W[i];
  }
}

// ---------------- Kernel 1: emissions = x @ W + b ----------------
// Class-set from blockIdx.y (SGPR-uniform by construction) -> W loads
// scalarize to s_load (SMEM pipe). x per-lane float4, prefetched 1 chunk.
#define EM_BODY(IT, CUR, NXT)                                                  \
  {                                                                            \
    if ((IT) + 1 < 24) {                                                       \
      _Pragma("unroll")                                                        \
      for (int q = 0; q < 8; ++q)                                              \
        xb[NXT][q] = *(const float4*)(xr + ((IT) + 1) * 32 + q * 4);           \
    }                                                                          \
    _Pragma("unroll")                                                          \
    for (int k = 0; k < 10; ++k) {                                             \
      int cc = cset + 4 * k;                                                   \
      if (cc < Cq) {                                                           \
        const float4* wr = (const float4*)(Wt + (size_t)cc * Dq + (IT) * 32);  \
        float a = acc[k];                                                      \
        _Pragma("unroll")                                                      \
        for (int q = 0; q < 8; ++q) {                                          \
          float4 w = wr[q];                                                    \
          a += xb[CUR][q].x * w.x; a += xb[CUR][q].y * w.y;                    \
          a += xb[CUR][q].z * w.z; a += xb[CUR][q].w * w.w;                    \
        }                                                                      \
        acc[k] = a;                                                            \
      }                                                                        \
    }                                                                          \
  }

__global__ __launch_bounds__(256) void emis_kernel(
    const float* __restrict__ x, const float* __restrict__ Wt,
    const float* __restrict__ bias, float* __restrict__ em)
{
  int tid = threadIdx.x;
  int cset = blockIdx.y;                               // 0..3, SGPR-uniform
  int tok = blockIdx.x * 256 + tid;
  const float* xr = x + (size_t)tok * Dq;
  float acc[10];
#pragma unroll
  for (int k = 0; k < 10; ++k) acc[k] = 0.f;
  float4 xb[2][8];
#pragma unroll
  for (int q = 0; q < 8; ++q) xb[0][q] = *(const float4*)(xr + q * 4);

#pragma unroll
  for (int kk = 0; kk < 12; ++kk) {
    EM_BODY(2 * kk, 0, 1)
    EM_BODY(2 * kk + 1, 1, 0)
  }
#pragma unroll
  for (int k = 0; k < 10; ++k) {
    int cc = cset + 4 * k;
    if (cc < Cq) em[(size_t)tok * Cq + cc] = acc[k] + bias[cc];
  }
}

// ---------------- Kernel 2: serial CRF (R8 structure, pk-packed inner) ----------------
__global__ __launch_bounds__(256) void crf_serial_kernel(
    const float* __restrict__ em, const float* __restrict__ startv,
    const float* __restrict__ endv, const float* __restrict__ trans,
    const int* __restrict__ labels, const unsigned char* __restrict__ maskb,
    float* __restrict__ vhist, float* __restrict__ llp,
    int* __restrict__ lenp, int* __restrict__ lastp)
{
  __shared__ float semm[(Sq + 4) * Cq];    // 516 rows: 4 pad rows kill clamps
  __shared__ float sexch[128];
  __shared__ float s_score, s_logZ;
  int b = blockIdx.x;
  int tid = threadIdx.x, wid = tid >> 6, lane = tid & 63;
  int cl = lane < Cq ? lane : Cq - 1;

  int esz4 = (maskb[1] == 0) ? 1 : 0;
  int len = 0;
#pragma unroll
  for (int k = 0; k < 8; ++k) {
    size_t t = (size_t)lane + (size_t)k * 64;
    unsigned char mb = esz4 ? maskb[((size_t)b * Sq + t) * 4] : maskb[(size_t)b * Sq + t];
    len += (mb != 0);
  }
#pragma unroll
  for (int off = 32; off; off >>= 1) len += __shfl_xor(len, off);

  // stage em[b] -> LDS; zero the 4 pad rows
  const float4* src4 = (const float4*)(em + (size_t)b * Sq * Cq);
  float4* dst4 = (float4*)semm;
  for (int i = tid; i < (Sq * Cq) / 4; i += 256) dst4[i] = src4[i];
  if (tid < 4 * Cq) semm[Sq * Cq + tid] = 0.f;
  __syncthreads();

  const float L2E = 1.4426950408889634f, LN2 = 0.6931471805599453f;

  if (wid == 0) {
    // ---- forward, exp domain; 18 pk_fma + 1 fma per step ----
    f32x2 E2[18];
#pragma unroll
    for (int i = 0; i < 18; ++i) {
      E2[i].x = exp2f(trans[(2 * i) * Cq + cl] * L2E);
      E2[i].y = exp2f(trans[(2 * i + 1) * Cq + cl] * L2E);
    }
    float E36 = exp2f(trans[36 * Cq + cl] * L2E);
    float* sE = sexch;
    const float4* se4 = (const float4*)sE;
    float a0 = (lane < Cq) ? (startv[cl] + semm[cl]) : -3.0e38f;
    float K0 = bcast(a0, 0);
    float ez = (lane < Cq) ? exp2f((a0 - K0) * L2E) : 0.f;
    int eacc = 0;
    float wA = exp2f(semm[1 * Cq + cl] * L2E), wB = exp2f(semm[2 * Cq + cl] * L2E);
    float wC = exp2f(semm[3 * Cq + cl] * L2E), wD = exp2f(semm[4 * Cq + cl] * L2E);
    for (int t = 1; t < len; ++t) {
      sE[lane] = ez;                                    // ds_write (in-order DS)
      float raw = semm[(t + 4) * Cq + cl];              // pad rows: no clamp
      float4 gv[10];
#pragma unroll
      for (int q = 0; q < 10; ++q) gv[q] = se4[q];      // 10x ds_read_b128 bcast
      int e0 = ((__float_as_int(gv[0].x) >> 23) & 255) - 127;
      float scale = __int_as_float((127 - e0) << 23);   // 2^-e0 exact
      f32x2 sa = {0.f, 0.f}, sb = {0.f, 0.f};
#define FPK(i) { f32x2 g; \
      if ((i) & 1) { g.x = gv[(i) >> 1].z; g.y = gv[(i) >> 1].w; } \
      else         { g.x = gv[(i) >> 1].x; g.y = gv[(i) >> 1].y; } \
      if ((i) & 1) sb = pk_fma(g, E2[i], sb); else sa = pk_fma(g, E2[i], sa); }
      REP18(FPK)
#undef FPK
      float dot = ((sa.x + sb.x) + (sa.y + sb.y)) + gv[9].x * E36;
      float wcur = wA; wA = wB; wB = wC; wC = wD;
      ez = dot * (wcur * scale);
      eacc += e0;
      wD = exp2f(raw * L2E);
    }
    float xv = (lane < Cq) ? LN2 * (log2f(ez) + (float)eacc) + K0 + endv[cl] : -3.0e38f;
    float mm = xv;
#pragma unroll
    for (int off = 32; off; off >>= 1) mm = fmaxf(mm, __shfl_xor(mm, off));
    float es = exp2f((xv - mm) * L2E);
#pragma unroll
    for (int off = 32; off; off >>= 1) es += __shfl_xor(es, off);
    if (lane == 0) s_logZ = mm + log2f(es) * LN2;
  } else if (wid == 1) {
    // ---- viterbi: 18 pk_add (exact) + max3 nests (exact) -> tags identical ----
    f32x2 T2[18];
#pragma unroll
    for (int i = 0; i < 18; ++i) {
      T2[i].x = trans[(2 * i) * Cq + cl];
      T2[i].y = trans[(2 * i + 1) * Cq + cl];
    }
    float T36 = trans[36 * Cq + cl];
    float* sV = sexch + 64;
    const float4* sv4 = (const float4*)sV;
    float v = (lane < Cq) ? (startv[cl] + semm[cl]) : -3.0e38f;
    if (lane < Cq) vhist[((size_t)b * Sq) * VST + cl] = v;
    float emA = semm[1 * Cq + cl], emB = semm[2 * Cq + cl];
    float emC = semm[3 * Cq + cl], emD = semm[4 * Cq + cl];
    for (int t = 1; t < len; ++t) {
      sV[lane] = v;
      float raw = semm[(t + 4) * Cq + cl];
      float4 gv[10];
#pragma unroll
      for (int q = 0; q < 10; ++q) gv[q] = sv4[q];
      float m0 = -3.0e38f, m1 = -3.0e38f, m2 = -3.0e38f, m3 = -3.0e38f;
#define VPK(i) { f32x2 g; \
      if ((i) & 1) { g.x = gv[(i) >> 1].z; g.y = gv[(i) >> 1].w; } \
      else         { g.x = gv[(i) >> 1].x; g.y = gv[(i) >> 1].y; } \
      f32x2 c = pk_add(g, T2[i]); \
      if (((i) & 3) == 0) m0 = fmaxf(fmaxf(m0, c.x), c.y); \
      else if (((i) & 3) == 1) m1 = fmaxf(fmaxf(m1, c.x), c.y); \
      else if (((i) & 3) == 2) m2 = fmaxf(fmaxf(m2, c.x), c.y); \
      else m3 = fmaxf(fmaxf(m3, c.x), c.y); }
      REP18(VPK)
#undef VPK
      float c36 = gv[9].x + T36;
      float best = fmaxf(fmaxf(fmaxf(m0, m1), fmaxf(m2, m3)), c36);
      float emc = emA; emA = emB; emB = emC; emC = emD;
      v = (lane < Cq) ? best + emc : -3.0e38f;
      if (lane < Cq) vhist[((size_t)b * Sq + t) * VST + cl] = v;
      emD = raw;
    }
    float xv = (lane < Cq) ? v + endv[cl] : -3.0e38f;
    int idx = (lane < Cq) ? lane : 1000;
#pragma unroll
    for (int off = 32; off; off >>= 1) {
      float xo = __shfl_xor(xv, off); int io = __shfl_xor(idx, off);
      if (xo > xv || (xo == xv && io < idx)) { xv = xo; idx = io; }
    }
    if (lane == 0) { lastp[b] = idx; lenp[b] = len; }
  } else if (wid == 2) {
    // ---- gold path score ----
    const int* lab = labels + (size_t)b * Sq;
    float sc = 0.f;
#pragma unroll
    for (int k = 0; k < 8; ++k) {
      int t = 1 + lane + k * 64;
      if (t < len) {
        int lp = lab[t - 1], lt = lab[t];
        sc += trans[lp * Cq + lt] + semm[t * Cq + lt];
      }
    }
#pragma unroll
    for (int off = 32; off; off >>= 1) sc += __shfl_xor(sc, off);
    if (lane == 0) {
      int l0 = lab[0], lf = lab[len - 1];
      s_score = sc + startv[l0] + semm[l0] + endv[lf];
    }
  }
  __syncthreads();
  if (tid == 0) llp[b] = s_score - s_logZ;
}

// ---------------- Kernel 3: backpointers (parallel recompute) ----------------
__global__ __launch_bounds__(256) void crf_bp_kernel(
    const float* __restrict__ vhist, const float* __restrict__ trans,
    const int* __restrict__ lenp, unsigned char* __restrict__ bp)
{
  int b = blockIdx.x >> 2, chunk = blockIdx.x & 3;
  int wid = threadIdx.x >> 6, lane = threadIdx.x & 63;
  int cl = lane < Cq ? lane : Cq - 1;
  int len = lenp[b];
#define DECLT(i) float T##i = trans[(i) * Cq + cl];
  REP37(DECLT)
  int tend = 1 + (chunk + 1) * 128; if (tend > len) tend = len;
  int rl9 = lane < VST ? lane : VST - 1;
  for (int t = 1 + chunk * 128 + wid; t < tend; t += 4) {
    float vr = vhist[((size_t)b * Sq + (t - 1)) * VST + rl9];
#define BCASTB(i) float br##i = bcast(vr, (i));
    REP37(BCASTB)
    float best = -3.0e38f; int bi = 0;
#define BARG(i) { float cnd = br##i + T##i; if (cnd > best) { best = cnd; bi = (i); } }
    REP37(BARG)                             // ascending + strict '>' => first-index tie-break
    if (lane < Cq) bp[((size_t)b * VST + cl) * Sq + t] = (unsigned char)bi;
  }
}

// ---------------- Kernel 4: register-resident backtrack ----------------
__global__ __launch_bounds__(64) void crf_back_kernel(
    const unsigned char* __restrict__ bp, const int* __restrict__ lenp,
    const int* __restrict__ lastp, float* __restrict__ outp)
{
  int b = blockIdx.x, lane = threadIdx.x;
  int len = __builtin_amdgcn_readfirstlane(lenp[b]);
  int tag = __builtin_amdgcn_readfirstlane(lastp[b]);
  int row = lane < VST ? lane : VST - 1;
  const uint4* src = (const uint4*)(bp + ((size_t)b * VST + row) * Sq);
  unsigned r[128];
#pragma unroll
  for (int k = 0; k < 32; ++k) {
    uint4 q = src[k];
    r[4 * k] = q.x; r[4 * k + 1] = q.y; r[4 * k + 2] = q.z; r[4 * k + 3] = q.w;
  }
  unsigned vt[8];
#pragma unroll
  for (int j = 0; j < 8; ++j) vt[j] = 0u;
  vt[7] = (lane == 63) ? (unsigned)tag : vt[7];
#pragma unroll
  for (int t = 510; t >= 0; --t) {
    int word = __builtin_amdgcn_readlane((int)r[(t + 1) >> 2], tag);
    int nt = (word >> (((t + 1) & 3) * 8)) & 0xff;
    tag = (t + 1 < len) ? nt : tag;
    vt[t >> 6] = (lane == (t & 63)) ? (unsigned)tag : vt[t >> 6];
  }
#pragma unroll
  for (int j = 0; j < 8; ++j) {
    int t = j * 64 + lane;
    float o = (t < len) ? (float)(int)vt[j] : 36.0f;
    outp[(size_t)b * Sq + t] = o;
  }
}

// ---------------- Kernel 5: reduce ll partials ----------------
__global__ __launch_bounds__(64) void ll_reduce_kernel(
    const float* __restrict__ llp, float* __restrict__ outp)
{
  int lane = threadIdx.x;
  float s = llp[lane] + llp[lane + 64];
#pragma unroll
  for (int off = 32; off; off >>= 1) s += __shfl_xor(s, off);
  if (lane == 0) outp[0] = s;
}

extern "C" void kernel_launch(void* const* d_in, const int* in_sizes, int n_in,
                              void* d_out, int out_size, void* d_ws, size_t ws_size,
                              hipStream_t stream)
{
  const float* x      = (const float*)d_in[0];
  const float* W      = (const float*)d_in[1];
  const float* bias   = (const float*)d_in[2];
  const float* startv = (const float*)d_in[3];
  const float* endv   = (const float*)d_in[4];
  const float* trans  = (const float*)d_in[5];
  const int*   labels = (const int*)d_in[6];
  const unsigned char* maskb = (const unsigned char*)d_in[7];
  float* out = (float*)d_out;

  char* ws = (char*)d_ws;
  float* em            = (float*)(ws);                    // 9,699,328 B
  float* vhist         = (float*)(ws + 9699328);          // 10,485,760 B
  unsigned char* bpbuf = (unsigned char*)(ws + 20185088); // 2,621,440 B
  float* llp           = (float*)(ws + 22806528);
  int*   lenp          = (int*)(ws + 22807552);
  int*   lastp         = (int*)(ws + 22808064);
  float* Wt            = (float*)(ws + 22808576);         // 113,664 B

  prep_kernel<<<28, 256, 0, stream>>>(W, Wt);
  emis_kernel<<<dim3(256, 4), 256, 0, stream>>>(x, Wt, bias, em);
  crf_serial_kernel<<<128, 256, 0, stream>>>(em, startv, endv, trans, labels, maskb,
                                             vhist, llp, lenp, lastp);
  crf_bp_kernel<<<512, 256, 0, stream>>>(vhist, trans, lenp, bpbuf);
  crf_back_kernel<<<128, 64, 0, stream>>>(bpbuf, lenp, lastp, out + 1);
  ll_reduce_kernel<<<1, 64, 0, stream>>>(llp, out);
}